// Round 13
// baseline (537.923 us; speedup 1.0000x reference)
//
#include <hip/hip_runtime.h>
#include <stdint.h>

#define T_LEN    1048576
#define TY_LEN   1048561
#define OUT_W    1048562
#define NM       32
#define WIN      16
#define NCH      4096
#define CL       256
#define CBT      256    // conv block threads (4 waves)
#define TPB      256    // timesteps per block == CL (one scan chunk per block)
#define XS_W     272    // 256 + 15 halo + pad; 32*272*4 = 34816 B
#define NF4      68     // XS_W/4 float4s per channel
#define YS_W     257    // y-in-LDS row stride (bank-conflict-free scan reads)

__device__ inline float sgnf(float a){
    return (a > 0.0f) ? 1.0f : ((a < 0.0f) ? -1.0f : 0.0f);
}

// ---------------- weight relayout: w[o][i][h] -> wT2[h][og][i][oi]
__global__ void wtrans_kernel(const float* __restrict__ w, float* __restrict__ wT2){
    const int idx = blockIdx.x * 256 + threadIdx.x;
    if (idx >= NM * NM * WIN) return;
    const int o = idx / (NM * WIN);
    const int r = idx - o * (NM * WIN);
    const int i = r / WIN;
    const int h = r - i * WIN;
    wT2[(((h * 4) + (o >> 3)) * NM + i) * 8 + (o & 7)] = w[idx];
}

// ---------------- conv + fused scan-pass-A.
// Conv order is XLA-CPU-faithful (h-major, i-minor, bias last); per-accumulator
// FMA chain operand-identical to all passing rounds. After the K-loop, y is
// staged in LDS (stride 257) and wave 0 computes this chunk's 4-candidate
// transition map from the identical y values -> bit-identical trans.
__global__ __launch_bounds__(256, 4) void conv_kernel(
    const float* __restrict__ x, const float* __restrict__ wT2,
    const float* __restrict__ b, const float* __restrict__ sp,
    const float* __restrict__ pwv, float* __restrict__ out,
    uint32_t* __restrict__ trans)
{
    __shared__ float xs[NM * XS_W];
    const int base = blockIdx.x * TPB;
    for (int idx = threadIdx.x; idx < NM * NF4; idx += CBT) {
        const int i = idx / NF4;
        const int q = idx - i * NF4;
        const int t0 = base + q * 4;
        float4 v;
        if (t0 + 3 < T_LEN) {
            v = *reinterpret_cast<const float4*>(x + (size_t)i * T_LEN + t0);
        } else {
            v.x = (t0 + 0 < T_LEN) ? x[(size_t)i * T_LEN + t0 + 0] : 0.0f;
            v.y = (t0 + 1 < T_LEN) ? x[(size_t)i * T_LEN + t0 + 1] : 0.0f;
            v.z = (t0 + 2 < T_LEN) ? x[(size_t)i * T_LEN + t0 + 2] : 0.0f;
            v.w = (t0 + 3 < T_LEN) ? x[(size_t)i * T_LEN + t0 + 3] : 0.0f;
        }
        *reinterpret_cast<float4*>(&xs[i * XS_W + q * 4]) = v;
    }
    __syncthreads();
    const int lane = threadIdx.x & 63;
    const int og   = __builtin_amdgcn_readfirstlane(threadIdx.x >> 6);
    float acc[8][4];
#pragma unroll
    for (int oi = 0; oi < 8; ++oi)
#pragma unroll
        for (int tt = 0; tt < 4; ++tt) acc[oi][tt] = 0.0f;
#pragma unroll 1
    for (int h = 0; h < WIN; ++h) {
        const float* wp = wT2 + (size_t)(h * 4 + og) * (NM * 8);  // uniform
#pragma unroll 1
        for (int c = 0; c < 4; ++c) {            // 8-i chunks
            float xv[8][4];
#pragma unroll
            for (int i2 = 0; i2 < 8; ++i2) {
                const int i = c * 8 + i2;
#pragma unroll
                for (int tt = 0; tt < 4; ++tt)
                    xv[i2][tt] = xs[i * XS_W + lane + 64 * tt + h];
            }
#pragma unroll
            for (int i2 = 0; i2 < 8; ++i2) {
                const float* wr = wp + (c * 8 + i2) * 8;   // 32 B, lane-uniform
#pragma unroll
                for (int oi = 0; oi < 8; ++oi) {
                    const float wv = wr[oi];
#pragma unroll
                    for (int tt = 0; tt < 4; ++tt)
                        acc[oi][tt] = fmaf(wv, xv[i2][tt], acc[oi][tt]);
                }
            }
        }
    }
    // ---- y = acc + bias: stage into LDS (reuse xs, stride 257) ----
    float yv[8][4];
    __syncthreads();   // all xs (staging) reads complete before overwrite
#pragma unroll
    for (int oi = 0; oi < 8; ++oi) {
        const int o = og * 8 + oi;
        const float bv = b[o];
#pragma unroll
        for (int tt = 0; tt < 4; ++tt) {
            yv[oi][tt] = acc[oi][tt] + bv;
            xs[o * YS_W + lane + 64 * tt] = yv[oi][tt];
        }
    }
    __syncthreads();   // y visible to the scan wave
    // ---- global y stores (all waves) ----
#pragma unroll
    for (int oi = 0; oi < 8; ++oi) {
        const int o = og * 8 + oi;
        float* orow = out + (size_t)o * OUT_W + 1 + base + lane;
#pragma unroll
        for (int tt = 0; tt < 4; ++tt) {
            const int t = base + lane + 64 * tt;
            if (t < TY_LEN) orow[64 * tt] = yv[oi][tt];
        }
    }
    // ---- fused scan-pass-A: wave 0, one lane per market ----
    if (threadIdx.x < NM) {
        const int m = threadIdx.x;
        const float pw = pwv[m];
        float p0 = -1.0f, p1 = 0.0f, p2 = 1.0f, p3 = sp[m];
        const int rem = TY_LEN - base;
        const int limit = rem < TPB ? rem : TPB;
        const float* yr = &xs[m * YS_W];
        for (int j = 0; j < limit; ++j) {
            const float hv = yr[j];
            p0 = sgnf(fmaf(p0, pw, hv));
            p1 = sgnf(fmaf(p1, pw, hv));
            p2 = sgnf(fmaf(p2, pw, hv));
            p3 = sgnf(fmaf(p3, pw, hv));
        }
        const uint32_t e0 = (uint32_t)((int)p0 + 1);
        const uint32_t e1 = (uint32_t)((int)p1 + 1);
        const uint32_t e2 = (uint32_t)((int)p2 + 1);
        const uint32_t e3 = (uint32_t)((int)p3 + 1);
        trans[m * NCH + blockIdx.x] = e0 | (e1 << 8) | (e2 << 16) | (e3 << 24);
    }
}

// ---------------- pass B: compose maps per market, emit entry state per chunk
__device__ inline uint32_t map_comp(uint32_t f, uint32_t g){
    uint32_t r = 0;
#pragma unroll
    for (int k = 0; k < 4; ++k) {
        const uint32_t s = (g >> (8 * k)) & 0xFFu;
        const uint32_t o = (f >> (8 * s)) & 0xFFu;
        r |= o << (8 * k);
    }
    return r;
}

__global__ __launch_bounds__(256) void scan_pass_b(
    const uint32_t* __restrict__ trans, uint8_t* __restrict__ entries)
{
    const uint32_t ID = 0x03020100u;   // identity; state 3 = raw start_pos
    const int m = blockIdx.x;
    const int tid = threadIdx.x;
    __shared__ uint32_t S[256];
    uint32_t maps[16];
    uint32_t seg = ID;
    const uint32_t* tr = trans + m * NCH + tid * 16;
#pragma unroll
    for (int j = 0; j < 16; ++j) { maps[j] = tr[j]; seg = map_comp(maps[j], seg); }
    S[tid] = seg;
    __syncthreads();
    for (int off = 1; off < 256; off <<= 1) {
        const uint32_t v = (tid >= off) ? S[tid - off] : ID;
        __syncthreads();
        if (tid >= off) S[tid] = map_comp(S[tid], v);
        __syncthreads();
    }
    const uint32_t pre = (tid == 0) ? ID : S[tid - 1];
    uint32_t s = (pre >> 24) & 0xFFu;   // prefix applied to initial state 3
    uint8_t* er = entries + m * NCH + tid * 16;
#pragma unroll
    for (int j = 0; j < 16; ++j) {
        er[j] = (uint8_t)s;
        s = (maps[j] >> (8 * s)) & 0xFFu;
    }
}

// ---------------- pass C: re-scan with known entry state; in-place y -> tanh
__global__ __launch_bounds__(256) void scan_pass_c(
    float* yo, const float* __restrict__ sp, const float* __restrict__ pwv,
    const uint8_t* __restrict__ entries)
{
    const int gid = blockIdx.x * 256 + threadIdx.x;
    const int m = gid >> 12;
    const int c = gid & (NCH - 1);
    const float pw = pwv[m];
    const float spv = sp[m];
    const uint32_t s = entries[m * NCH + c];
    float p = (s == 3u) ? spv : ((float)(int)s - 1.0f);
    float* row = yo + (size_t)m * OUT_W + 1 + c * CL;
    if (c == 0) yo[(size_t)m * OUT_W] = spv;
    const int limit0 = TY_LEN - c * CL;
    const int limit = limit0 < CL ? limit0 : CL;
    int j = 0;
    for (; j + 4 <= limit; j += 4) {
        const float4 h = *reinterpret_cast<const float4*>(row + j);
        float a;
        a = fmaf(p, pw, h.x); row[j+0] = tanhf(a); p = sgnf(a);
        a = fmaf(p, pw, h.y); row[j+1] = tanhf(a); p = sgnf(a);
        a = fmaf(p, pw, h.z); row[j+2] = tanhf(a); p = sgnf(a);
        a = fmaf(p, pw, h.w); row[j+3] = tanhf(a); p = sgnf(a);
    }
    for (; j < limit; ++j) {
        const float a = fmaf(p, pw, row[j]);
        row[j] = tanhf(a);
        p = sgnf(a);
    }
}

extern "C" void kernel_launch(void* const* d_in, const int* in_sizes, int n_in,
                              void* d_out, int out_size, void* d_ws, size_t ws_size,
                              hipStream_t stream)
{
    const float* x   = (const float*)d_in[0];
    const float* spv = (const float*)d_in[1];
    const float* w   = (const float*)d_in[2];
    const float* b   = (const float*)d_in[3];
    const float* pw  = (const float*)d_in[4];
    float* out = (float*)d_out;

    // workspace: wT2 64 KiB | trans 512 KiB | entries 128 KiB
    uint8_t* ws = (uint8_t*)d_ws;
    float*    wT2     = (float*)ws;
    uint32_t* trans   = (uint32_t*)(ws + 65536);
    uint8_t*  entries = (uint8_t*)(ws + 65536 + 524288);

    const int conv_blocks = NCH;   // 4096 blocks == 4096 scan chunks
    wtrans_kernel<<<64, 256, 0, stream>>>(w, wT2);
    conv_kernel<<<conv_blocks, CBT, 0, stream>>>(x, wT2, b, spv, pw, out, trans);
    scan_pass_b<<<NM, 256, 0, stream>>>(trans, entries);
    scan_pass_c<<<(NM * NCH) / 256, 256, 0, stream>>>(out, spv, pw, entries);
}

// Round 14
// 501.434 us; speedup vs baseline: 1.0728x; 1.0728x over previous
//
#include <hip/hip_runtime.h>
#include <stdint.h>

#define T_LEN    1048576
#define TY_LEN   1048561
#define OUT_W    1048562
#define NM       32
#define WIN      16
#define NCH      4096
#define CL       256
#define CBT      256    // conv block threads (4 waves)
#define TPB      256    // timesteps per block == CL (one scan chunk per block)
#define XS_W     272    // 256 + 15 halo + pad; 32*272*4 = 34816 B
#define NF4      68     // XS_W/4 float4s per channel
#define YS_W     257    // y-in-LDS row stride

__device__ inline float sgnf(float a){
    return (a > 0.0f) ? 1.0f : ((a < 0.0f) ? -1.0f : 0.0f);
}

__device__ inline uint32_t map_comp(uint32_t f, uint32_t g){
    // (f o g)(s) = f(g(s)); byte k of result = f[g[k]]
    uint32_t r = 0;
#pragma unroll
    for (int k = 0; k < 4; ++k) {
        const uint32_t s = (g >> (8 * k)) & 0xFFu;
        const uint32_t o = (f >> (8 * s)) & 0xFFu;
        r |= o << (8 * k);
    }
    return r;
}

// ---------------- weight relayout: w[o][i][h] -> wT2[h][og][i][oi]
__global__ void wtrans_kernel(const float* __restrict__ w, float* __restrict__ wT2){
    const int idx = blockIdx.x * 256 + threadIdx.x;
    if (idx >= NM * NM * WIN) return;
    const int o = idx / (NM * WIN);
    const int r = idx - o * (NM * WIN);
    const int i = r / WIN;
    const int h = r - i * WIN;
    wT2[(((h * 4) + (o >> 3)) * NM + i) * 8 + (o & 7)] = w[idx];
}

// ---------------- conv + fused scan-pass-A (parallel subchunk maps).
// Conv order is XLA-CPU-faithful (h-major, i-minor, bias last); per-accumulator
// FMA chain operand-identical to all passing rounds. Scan-A: thread =
// (market, subchunk of 32 steps); 8 maps composed exactly -> bit-identical trans.
__global__ __launch_bounds__(256, 4) void conv_kernel(
    const float* __restrict__ x, const float* __restrict__ wT2,
    const float* __restrict__ b, const float* __restrict__ sp,
    const float* __restrict__ pwv, float* __restrict__ out,
    uint32_t* __restrict__ trans)
{
    __shared__ float xs[NM * XS_W];
    __shared__ uint32_t maps8[NM * 8];
    const int base = blockIdx.x * TPB;
    for (int idx = threadIdx.x; idx < NM * NF4; idx += CBT) {
        const int i = idx / NF4;
        const int q = idx - i * NF4;
        const int t0 = base + q * 4;
        float4 v;
        if (t0 + 3 < T_LEN) {
            v = *reinterpret_cast<const float4*>(x + (size_t)i * T_LEN + t0);
        } else {
            v.x = (t0 + 0 < T_LEN) ? x[(size_t)i * T_LEN + t0 + 0] : 0.0f;
            v.y = (t0 + 1 < T_LEN) ? x[(size_t)i * T_LEN + t0 + 1] : 0.0f;
            v.z = (t0 + 2 < T_LEN) ? x[(size_t)i * T_LEN + t0 + 2] : 0.0f;
            v.w = (t0 + 3 < T_LEN) ? x[(size_t)i * T_LEN + t0 + 3] : 0.0f;
        }
        *reinterpret_cast<float4*>(&xs[i * XS_W + q * 4]) = v;
    }
    __syncthreads();
    const int lane = threadIdx.x & 63;
    const int og   = __builtin_amdgcn_readfirstlane(threadIdx.x >> 6);
    float acc[8][4];
#pragma unroll
    for (int oi = 0; oi < 8; ++oi)
#pragma unroll
        for (int tt = 0; tt < 4; ++tt) acc[oi][tt] = 0.0f;
#pragma unroll 1
    for (int h = 0; h < WIN; ++h) {
        const float* wp = wT2 + (size_t)(h * 4 + og) * (NM * 8);  // uniform
#pragma unroll 1
        for (int c = 0; c < 4; ++c) {            // 8-i chunks
            float xv[8][4];
#pragma unroll
            for (int i2 = 0; i2 < 8; ++i2) {
                const int i = c * 8 + i2;
#pragma unroll
                for (int tt = 0; tt < 4; ++tt)
                    xv[i2][tt] = xs[i * XS_W + lane + 64 * tt + h];
            }
#pragma unroll
            for (int i2 = 0; i2 < 8; ++i2) {
                const float* wr = wp + (c * 8 + i2) * 8;   // 32 B, lane-uniform
#pragma unroll
                for (int oi = 0; oi < 8; ++oi) {
                    const float wv = wr[oi];
#pragma unroll
                    for (int tt = 0; tt < 4; ++tt)
                        acc[oi][tt] = fmaf(wv, xv[i2][tt], acc[oi][tt]);
                }
            }
        }
    }
    // ---- y = acc + bias: stage into LDS (reuse xs, stride 257) ----
    float yv[8][4];
    __syncthreads();   // staging reads of xs complete before overwrite
#pragma unroll
    for (int oi = 0; oi < 8; ++oi) {
        const int o = og * 8 + oi;
        const float bv = b[o];
#pragma unroll
        for (int tt = 0; tt < 4; ++tt) {
            yv[oi][tt] = acc[oi][tt] + bv;
            xs[o * YS_W + lane + 64 * tt] = yv[oi][tt];
        }
    }
    __syncthreads();   // y visible to all scan threads
    // ---- global y stores (all waves) ----
#pragma unroll
    for (int oi = 0; oi < 8; ++oi) {
        const int o = og * 8 + oi;
        float* orow = out + (size_t)o * OUT_W + 1 + base + lane;
#pragma unroll
        for (int tt = 0; tt < 4; ++tt) {
            const int t = base + lane + 64 * tt;
            if (t < TY_LEN) orow[64 * tt] = yv[oi][tt];
        }
    }
    // ---- fused scan-A: thread = (market, 32-step subchunk), all 256 active ----
    {
        const int sm = threadIdx.x >> 3;   // market
        const int ss = threadIdx.x & 7;    // subchunk index
        const float pws = pwv[sm];
        float q0 = -1.0f, q1 = 0.0f, q2 = 1.0f, q3 = sp[sm];
        const int rem = TY_LEN - base;
        int st = rem - ss * 32; st = st < 0 ? 0 : (st > 32 ? 32 : st);
        const float* yr = &xs[sm * YS_W + ss * 32];
        for (int j = 0; j < st; ++j) {
            const float hv = yr[j];
            q0 = sgnf(fmaf(q0, pws, hv));
            q1 = sgnf(fmaf(q1, pws, hv));
            q2 = sgnf(fmaf(q2, pws, hv));
            q3 = sgnf(fmaf(q3, pws, hv));
        }
        const uint32_t e0 = (uint32_t)((int)q0 + 1);
        const uint32_t e1 = (uint32_t)((int)q1 + 1);
        const uint32_t e2 = (uint32_t)((int)q2 + 1);
        const uint32_t e3 = (st == 0) ? 3u : (uint32_t)((int)q3 + 1);
        maps8[sm * 8 + ss] = e0 | (e1 << 8) | (e2 << 16) | (e3 << 24);
    }
    __syncthreads();
    if (threadIdx.x < NM) {
        uint32_t seg = 0x03020100u;
#pragma unroll
        for (int s = 0; s < 8; ++s)
            seg = map_comp(maps8[threadIdx.x * 8 + s], seg);
        trans[threadIdx.x * NCH + blockIdx.x] = seg;
    }
}

// ---------------- pass B: compose maps per market, emit entry state per chunk
__global__ __launch_bounds__(256) void scan_pass_b(
    const uint32_t* __restrict__ trans, uint8_t* __restrict__ entries)
{
    const uint32_t ID = 0x03020100u;   // identity; state 3 = raw start_pos
    const int m = blockIdx.x;
    const int tid = threadIdx.x;
    __shared__ uint32_t S[256];
    uint32_t maps[16];
    uint32_t seg = ID;
    const uint32_t* tr = trans + m * NCH + tid * 16;
#pragma unroll
    for (int j = 0; j < 16; ++j) { maps[j] = tr[j]; seg = map_comp(maps[j], seg); }
    S[tid] = seg;
    __syncthreads();
    for (int off = 1; off < 256; off <<= 1) {
        const uint32_t v = (tid >= off) ? S[tid - off] : ID;
        __syncthreads();
        if (tid >= off) S[tid] = map_comp(S[tid], v);
        __syncthreads();
    }
    const uint32_t pre = (tid == 0) ? ID : S[tid - 1];
    uint32_t s = (pre >> 24) & 0xFFu;   // prefix applied to initial state 3
    uint8_t* er = entries + m * NCH + tid * 16;
#pragma unroll
    for (int j = 0; j < 16; ++j) {
        er[j] = (uint8_t)s;
        s = (maps[j] >> (8 * s)) & 0xFFu;
    }
}

// ---------------- pass C: re-scan with known entry state; in-place y -> tanh
__global__ __launch_bounds__(256) void scan_pass_c(
    float* yo, const float* __restrict__ sp, const float* __restrict__ pwv,
    const uint8_t* __restrict__ entries)
{
    const int gid = blockIdx.x * 256 + threadIdx.x;
    const int m = gid >> 12;
    const int c = gid & (NCH - 1);
    const float pw = pwv[m];
    const float spv = sp[m];
    const uint32_t s = entries[m * NCH + c];
    float p = (s == 3u) ? spv : ((float)(int)s - 1.0f);
    float* row = yo + (size_t)m * OUT_W + 1 + c * CL;
    if (c == 0) yo[(size_t)m * OUT_W] = spv;
    const int limit0 = TY_LEN - c * CL;
    const int limit = limit0 < CL ? limit0 : CL;
    int j = 0;
    for (; j + 4 <= limit; j += 4) {
        const float4 h = *reinterpret_cast<const float4*>(row + j);
        float a;
        a = fmaf(p, pw, h.x); row[j+0] = tanhf(a); p = sgnf(a);
        a = fmaf(p, pw, h.y); row[j+1] = tanhf(a); p = sgnf(a);
        a = fmaf(p, pw, h.z); row[j+2] = tanhf(a); p = sgnf(a);
        a = fmaf(p, pw, h.w); row[j+3] = tanhf(a); p = sgnf(a);
    }
    for (; j < limit; ++j) {
        const float a = fmaf(p, pw, row[j]);
        row[j] = tanhf(a);
        p = sgnf(a);
    }
}

extern "C" void kernel_launch(void* const* d_in, const int* in_sizes, int n_in,
                              void* d_out, int out_size, void* d_ws, size_t ws_size,
                              hipStream_t stream)
{
    const float* x   = (const float*)d_in[0];
    const float* spv = (const float*)d_in[1];
    const float* w   = (const float*)d_in[2];
    const float* b   = (const float*)d_in[3];
    const float* pw  = (const float*)d_in[4];
    float* out = (float*)d_out;

    // workspace: wT2 64 KiB | trans 512 KiB | entries 128 KiB
    uint8_t* ws = (uint8_t*)d_ws;
    float*    wT2     = (float*)ws;
    uint32_t* trans   = (uint32_t*)(ws + 65536);
    uint8_t*  entries = (uint8_t*)(ws + 65536 + 524288);

    wtrans_kernel<<<64, 256, 0, stream>>>(w, wT2);
    conv_kernel<<<NCH, CBT, 0, stream>>>(x, wT2, b, spv, pw, out, trans);
    scan_pass_b<<<NM, 256, 0, stream>>>(trans, entries);
    scan_pass_c<<<(NM * NCH) / 256, 256, 0, stream>>>(out, spv, pw, entries);
}